// Round 4
// baseline (370.587 us; speedup 1.0000x reference)
//
#include <hip/hip_runtime.h>
#include <math.h>

// Multi-scale region distillation loss — v4: transposed two-pass for DRAM locality.
// Pass 1: block = (scale, b, 32-ch chunk, pixel-tile P). Stages one channel-pair
// per step into LDS via global_load_lds (8 KB contiguous per tensor), accumulates
// dot/na2/nb2 per pixel in REGISTERS across the 32 channels, writes fp32 partials
// (3 x P floats) to ws. Pass 2: per pixel-group, reduce 8 chunk-partials ->
// cosine -> label -> shared bins -> global bins. Pass 3: finalize loss.
// ws layout: [0..255] class bins (sim/cnt per scale); [256..] partials (16.7 MB).

#define EPSV 1e-8f

// partial-region float offsets (within ws+256)
#define P_S1 3145728   // 512 blocks * 3*2048
#define P_S2 3932160   // + 128 * 3*2048
#define P_S3 4128768   // + 64 * 3*1024
#define P_END 4177920  // + 64 * 3*256
#define WS_NEEDED ((256 + P_END) * sizeof(float))

typedef const __attribute__((address_space(1))) void GV;
typedef __attribute__((address_space(3))) void LV;

__device__ __forceinline__ void gl_lds16(const float* gp, float* lp) {
    __builtin_amdgcn_global_load_lds((GV*)gp, (LV*)lp, 16, 0, 0);
}

__global__ __launch_bounds__(256)
void msrd_pass1(const float* __restrict__ f0, const float* __restrict__ fo0,
                const float* __restrict__ f1, const float* __restrict__ fo1,
                const float* __restrict__ f2, const float* __restrict__ fo2,
                const float* __restrict__ f3, const float* __restrict__ fo3,
                float* __restrict__ part)   // ws + 256
{
    const int bid = blockIdx.x;
    int idx, logT, logHW, P;  const float *f, *fo; float* pbase;
    // blocks: [0,512) s0, [512,640) s1, [640,704) s2, [704,768) s3
    if (bid < 512)      { idx = bid;      logT=3; logHW=14; P=2048; f=f0; fo=fo0; pbase = part; }
    else if (bid < 640) { idx = bid-512;  logT=1; logHW=12; P=2048; f=f1; fo=fo1; pbase = part + P_S1; }
    else if (bid < 704) { idx = bid-640;  logT=0; logHW=10; P=1024; f=f2; fo=fo2; pbase = part + P_S2; }
    else                { idx = bid-704;  logT=0; logHW=8;  P=256;  f=f3; fo=fo3; pbase = part + P_S3; }
    const int chunk = idx & 7;
    const int tile  = (idx >> 3) & ((1 << logT) - 1);
    const int b     = idx >> (3 + logT);
    const int bt    = (b << logT) + tile;

    const int tid = threadIdx.x, wave = tid >> 6, lane = tid & 63;

    __shared__ float stage[2][2][2048];   // [buf][tensor][px]  32 KB

    const size_t base_off = (((size_t)(b * 256 + chunk * 32)) << logHW)
                          + (size_t)tile * P;      // element offset of (b, c0, tile*P)
    const int nI = P >> 8;                         // 1KB wave-instrs per tensor per stage

    float dA[2][4], nA[2][4], nB[2][4];
    #pragma unroll
    for (int j = 0; j < 2; ++j)
        for (int k = 0; k < 4; ++k) { dA[j][k]=0.f; nA[j][k]=0.f; nB[j][k]=0.f; }

    #define ISSUE(s, bf) do {                                                    \
        const size_t co = base_off + (((size_t)(s)) << logHW);                   \
        for (int i = wave; i < nI; i += 4) {                                     \
            gl_lds16(f  + co + i * 256 + lane * 4, &stage[bf][0][i * 256]);      \
            gl_lds16(fo + co + i * 256 + lane * 4, &stage[bf][1][i * 256]);      \
        } } while (0)

    ISSUE(0, 0);
    __syncthreads();

    #pragma unroll 1
    for (int s = 0; s < 32; ++s) {
        const int buf = s & 1;
        if (s < 31) ISSUE(s + 1, buf ^ 1);
        #pragma unroll
        for (int j = 0; j < 2; ++j) {
            const int g = tid + (j << 8);          // float4-group
            if ((g << 2) < P) {
                float4 x = *(const float4*)&stage[buf][0][g << 2];
                float4 y = *(const float4*)&stage[buf][1][g << 2];
                dA[j][0]=fmaf(x.x,y.x,dA[j][0]); dA[j][1]=fmaf(x.y,y.y,dA[j][1]);
                dA[j][2]=fmaf(x.z,y.z,dA[j][2]); dA[j][3]=fmaf(x.w,y.w,dA[j][3]);
                nA[j][0]=fmaf(x.x,x.x,nA[j][0]); nA[j][1]=fmaf(x.y,x.y,nA[j][1]);
                nA[j][2]=fmaf(x.z,x.z,nA[j][2]); nA[j][3]=fmaf(x.w,x.w,nA[j][3]);
                nB[j][0]=fmaf(y.x,y.x,nB[j][0]); nB[j][1]=fmaf(y.y,y.y,nB[j][1]);
                nB[j][2]=fmaf(y.z,y.z,nB[j][2]); nB[j][3]=fmaf(y.w,y.w,nB[j][3]);
            }
        }
        __syncthreads();
    }
    #undef ISSUE

    float* outb = pbase + (size_t)(bt * 8 + chunk) * 3 * P;
    #pragma unroll
    for (int j = 0; j < 2; ++j) {
        const int g = tid + (j << 8);
        if ((g << 2) < P) {
            *(float4*)&outb[g << 2]           = make_float4(dA[j][0],dA[j][1],dA[j][2],dA[j][3]);
            *(float4*)&outb[P + (g << 2)]     = make_float4(nA[j][0],nA[j][1],nA[j][2],nA[j][3]);
            *(float4*)&outb[2 * P + (g << 2)] = make_float4(nB[j][0],nB[j][1],nB[j][2],nB[j][3]);
        }
    }
}

__global__ __launch_bounds__(256)
void msrd_pass2(const float* __restrict__ part, const int* __restrict__ labels,
                const int* __restrict__ p_nclass, float* __restrict__ bins)
{
    const int gid = blockIdx.x * 256 + threadIdx.x;
    int scale, bt, g, logT, logW, sshift, P; const float* pbase;
    // group ranges: [0,32768) s0, [32768,40960) s1, [40960,43008) s2, [43008,43520) s3
    if (gid < 32768)      { scale=0; int q=gid;         bt=q>>9; g=q&511; logT=3; logW=7; sshift=2; P=2048; pbase=part; }
    else if (gid < 40960) { scale=1; int q=gid-32768;   bt=q>>9; g=q&511; logT=1; logW=6; sshift=3; P=2048; pbase=part+P_S1; }
    else if (gid < 43008) { scale=2; int q=gid-40960;   bt=q>>8; g=q&255; logT=0; logW=5; sshift=4; P=1024; pbase=part+P_S2; }
    else                  { scale=3; int q=gid-43008;   bt=q>>6; g=q&63;  logT=0; logW=4; sshift=5; P=256;  pbase=part+P_S3; }

    __shared__ float bin_sim[32], bin_cnt[32];
    if (threadIdx.x < 32) { bin_sim[threadIdx.x] = 0.f; bin_cnt[threadIdx.x] = 0.f; }
    __syncthreads();

    float D[4] = {0,0,0,0}, A[4] = {0,0,0,0}, Bv[4] = {0,0,0,0};
    const float* pb = pbase + (size_t)bt * 8 * 3 * P;
    #pragma unroll
    for (int c = 0; c < 8; ++c) {
        const float* cb = pb + (size_t)c * 3 * P;
        float4 d = *(const float4*)&cb[g << 2];
        float4 a = *(const float4*)&cb[P + (g << 2)];
        float4 bb = *(const float4*)&cb[2 * P + (g << 2)];
        D[0]+=d.x; D[1]+=d.y; D[2]+=d.z; D[3]+=d.w;
        A[0]+=a.x; A[1]+=a.y; A[2]+=a.z; A[3]+=a.w;
        Bv[0]+=bb.x; Bv[1]+=bb.y; Bv[2]+=bb.z; Bv[3]+=bb.w;
    }

    const int b    = bt >> logT;
    const int tile = bt & ((1 << logT) - 1);
    const int W    = 1 << logW;
    const int nclass = *p_nclass;
    #pragma unroll
    for (int j = 0; j < 4; ++j) {
        float na  = fmaxf(sqrtf(A[j]), EPSV);
        float nb  = fmaxf(sqrtf(Bv[j]), EPSV);
        float sim = D[j] / (na * nb);
        int p    = tile * P + (g << 2) + j;       // flat pixel in image plane
        int h    = p >> logW;
        int col  = p & (W - 1);
        int lidx = (b << 18) + ((h << sshift) << 9) + (col << sshift);
        int lab  = labels[lidx];
        if ((unsigned)lab < (unsigned)nclass) {
            atomicAdd(&bin_sim[lab], sim);
            atomicAdd(&bin_cnt[lab], 1.0f);
        }
    }
    __syncthreads();

    if (threadIdx.x < 32) {
        float sv = bin_sim[threadIdx.x], cv = bin_cnt[threadIdx.x];
        if (sv != 0.f || cv != 0.f) {
            atomicAdd(&bins[scale * 64 + threadIdx.x],      sv);
            atomicAdd(&bins[scale * 64 + 32 + threadIdx.x], cv);
        }
    }
}

// ---- fallback (v1, known-correct) for undersized ws ----
__global__ __launch_bounds__(512)
void msrd_fb(const float* __restrict__ f0, const float* __restrict__ fo0,
             const float* __restrict__ f1, const float* __restrict__ fo1,
             const float* __restrict__ f2, const float* __restrict__ fo2,
             const float* __restrict__ f3, const float* __restrict__ fo3,
             const int* __restrict__ labels, const int* __restrict__ p_nclass,
             float* __restrict__ ws)
{
    int bid = blockIdx.x;
    int scale, lb, logW, logHW, sshift;
    const float *f, *fo;
    if (bid < 512)      { scale = 0; lb = bid;       f = f0; fo = fo0; logW = 7; logHW = 14; sshift = 2; }
    else if (bid < 640) { scale = 1; lb = bid - 512; f = f1; fo = fo1; logW = 6; logHW = 12; sshift = 3; }
    else if (bid < 672) { scale = 2; lb = bid - 640; f = f2; fo = fo2; logW = 5; logHW = 10; sshift = 4; }
    else                { scale = 3; lb = bid - 672; f = f3; fo = fo3; logW = 4; logHW = 8;  sshift = 5; }
    const int HW = 1 << logHW, W = 1 << logW;
    const int tid = threadIdx.x, wave = tid >> 6, lane = tid & 63;
    const int pix = (lb * 64 + lane) << 2;
    const int b = pix >> logHW, rem = pix & (HW - 1);
    const float4* fp  = (const float4*)(f  + (size_t)(b * 256 + wave * 32) * HW + rem);
    const float4* fop = (const float4*)(fo + (size_t)(b * 256 + wave * 32) * HW + rem);
    const int str4 = HW >> 2;
    float dx=0,dy=0,dz=0,dw=0, ax=0,ay=0,az=0,aw=0, bx=0,by=0,bz=0,bw=0;
    #pragma unroll 4
    for (int c = 0; c < 32; ++c) {
        float4 x = fp[c * str4], y = fop[c * str4];
        dx=fmaf(x.x,y.x,dx); dy=fmaf(x.y,y.y,dy); dz=fmaf(x.z,y.z,dz); dw=fmaf(x.w,y.w,dw);
        ax=fmaf(x.x,x.x,ax); ay=fmaf(x.y,x.y,ay); az=fmaf(x.z,x.z,az); aw=fmaf(x.w,x.w,aw);
        bx=fmaf(y.x,y.x,bx); by=fmaf(y.y,y.y,by); bz=fmaf(y.z,y.z,bz); bw=fmaf(y.w,y.w,bw);
    }
    __shared__ float4 sD[8][64], sA[8][64], sB[8][64];
    __shared__ float bin_sim[32], bin_cnt[32];
    if (tid < 32) { bin_sim[tid]=0.f; bin_cnt[tid]=0.f; }
    sD[wave][lane]=make_float4(dx,dy,dz,dw);
    sA[wave][lane]=make_float4(ax,ay,az,aw);
    sB[wave][lane]=make_float4(bx,by,bz,bw);
    __syncthreads();
    if (wave == 0) {
        float4 D=sD[0][lane], A=sA[0][lane], Bv=sB[0][lane];
        #pragma unroll
        for (int w = 1; w < 8; ++w) {
            float4 t;
            t=sD[w][lane]; D.x+=t.x;D.y+=t.y;D.z+=t.z;D.w+=t.w;
            t=sA[w][lane]; A.x+=t.x;A.y+=t.y;A.z+=t.z;A.w+=t.w;
            t=sB[w][lane]; Bv.x+=t.x;Bv.y+=t.y;Bv.z+=t.z;Bv.w+=t.w;
        }
        const int nclass = *p_nclass;
        float Dv[4]={D.x,D.y,D.z,D.w}, Av[4]={A.x,A.y,A.z,A.w}, Bw[4]={Bv.x,Bv.y,Bv.z,Bv.w};
        #pragma unroll
        for (int j = 0; j < 4; ++j) {
            float na=fmaxf(sqrtf(Av[j]),EPSV), nb=fmaxf(sqrtf(Bw[j]),EPSV);
            float sim = Dv[j]/(na*nb);
            int p=rem+j, h=p>>logW, col=p&(W-1);
            int lidx=(b<<18)+((h<<sshift)<<9)+(col<<sshift);
            int lab=labels[lidx];
            if ((unsigned)lab < (unsigned)nclass) {
                atomicAdd(&bin_sim[lab], sim);
                atomicAdd(&bin_cnt[lab], 1.0f);
            }
        }
    }
    __syncthreads();
    if (tid < 32) {
        float s=bin_sim[tid], c=bin_cnt[tid];
        if (s!=0.f || c!=0.f) {
            atomicAdd(&ws[scale*64+tid], s);
            atomicAdd(&ws[scale*64+32+tid], c);
        }
    }
}

__global__ void msrd_final(const float* __restrict__ bins,
                           const int* __restrict__ p_nclass,
                           const int* __restrict__ p_nold,
                           float* __restrict__ out)
{
    if (threadIdx.x == 0 && blockIdx.x == 0) {
        const int nc = *p_nclass;
        const int no = *p_nold;
        const float wgt[4] = {1.f, 2.f, 3.f, 4.f};
        float loss = 0.f;
        for (int s = 0; s < 4; ++s) {
            float sl = 0.f;
            for (int c = 0; c < nc && c < 32; ++c) {
                float seg = bins[s * 64 + c];
                float cnt = bins[s * 64 + 32 + c];
                if (cnt > 0.f) {
                    float factor = (c == 0) ? (float)no / (float)nc
                                            : (c <= no ? 1.f : 0.f);
                    sl += factor * (1.f - seg / fmaxf(cnt, 1.f));
                }
            }
            loss += wgt[s] * sl;
        }
        out[0] = loss;
    }
}

extern "C" void kernel_launch(void* const* d_in, const int* in_sizes, int n_in,
                              void* d_out, int out_size, void* d_ws, size_t ws_size,
                              hipStream_t stream) {
    const int*   labels = (const int*)  d_in[0];
    const float* f0  = (const float*)d_in[1];
    const float* fo0 = (const float*)d_in[2];
    const float* f1  = (const float*)d_in[3];
    const float* fo1 = (const float*)d_in[4];
    const float* f2  = (const float*)d_in[5];
    const float* fo2 = (const float*)d_in[6];
    const float* f3  = (const float*)d_in[7];
    const float* fo3 = (const float*)d_in[8];
    const int* p_nclass = (const int*)d_in[9];
    const int* p_nold   = (const int*)d_in[10];
    float* out = (float*)d_out;
    float* ws  = (float*)d_ws;

    hipMemsetAsync(ws, 0, 256 * sizeof(float), stream);   // class bins only
    if (ws_size >= WS_NEEDED) {
        msrd_pass1<<<dim3(768), dim3(256), 0, stream>>>(f0, fo0, f1, fo1, f2, fo2, f3, fo3,
                                                        ws + 256);
        msrd_pass2<<<dim3(170), dim3(256), 0, stream>>>(ws + 256, labels, p_nclass, ws);
    } else {
        msrd_fb<<<dim3(680), dim3(512), 0, stream>>>(f0, fo0, f1, fo1, f2, fo2, f3, fo3,
                                                     labels, p_nclass, ws);
    }
    msrd_final<<<dim3(1), dim3(64), 0, stream>>>(ws, p_nclass, p_nold, out);
}